// Round 16
// baseline (1140.581 us; speedup 1.0000x reference)
//
#include <hip/hip_runtime.h>
#include <hip/hip_bf16.h>

// ---------------------------------------------------------------------------
// SimpleGeoFormerModel: 4-layer transformer encoder. FP32 out; bf16
// activations/weights/residual/partials; MFMA fp32 accumulate.
// B=8 N=256 E=512 V=512 L=4 H=8 FF=2048, dh=64.
// Round 16: split-K collector — the last-arriving GEMM block performs the
// partial-sum + residual + bias + LayerNorm in-kernel (removes all 8 addln
// launches). Device-scope atomics + fences; deterministic (fixed sum order).
// ---------------------------------------------------------------------------

namespace {
constexpr int Bn  = 8;
constexpr int Nn  = 256;
constexpr int En  = 512;
constexpr int Ln  = 4;
constexpr int Hn  = 8;
constexpr int FFn = 2048;
constexpr int DHn = 64;
constexpr int Mn  = Bn * Nn;        // 2048 rows
constexpr int QKV_LD = 3 * En;      // 1536
constexpr int LUT_N = 4096;
}

typedef float f32x4 __attribute__((ext_vector_type(4)));
typedef short bf16x8 __attribute__((ext_vector_type(8)));

// fp32 -> bf16 round-to-nearest-even (finite inputs)
__device__ __forceinline__ unsigned short f2bs(float f) {
    union { float f; unsigned u; } v; v.f = f;
    unsigned r = v.u + 0x7FFFu + ((v.u >> 16) & 1u);
    return (unsigned short)(r >> 16);
}
__device__ __forceinline__ float bf2f(unsigned short s) {
    union { unsigned u; float f; } v;
    v.u = ((unsigned)s) << 16;
    return v.f;
}

// swizzled byte address within a row-major bf16 LDS tile (16B-unit XOR)
__device__ __forceinline__ int swz(int row, int byte_in_row, int stride_b) {
    return row * stride_b + (byte_in_row ^ ((row & 7) << 4));
}

// async global->LDS, 16B per lane; LDS dest = wave-uniform base + lane*16
__device__ __forceinline__ void gload_lds16(const void* g, void* l) {
    __builtin_amdgcn_global_load_lds(
        (const __attribute__((address_space(1))) unsigned int*)g,
        (__attribute__((address_space(3))) unsigned int*)l,
        16, 0, 0);
}

// ---------------- one-shot weight conversion (4 ranges, 1 launch) ----------
struct CvtArgs {
    const float* src[4];
    unsigned short* dst[4];
    int n4[4];
    int blkoff[5];
};
__global__ __launch_bounds__(256) void k_cvt(CvtArgs a) {
    int bid = blockIdx.x;
    int r = 0;
    if (bid >= a.blkoff[1]) r = 1;
    if (bid >= a.blkoff[2]) r = 2;
    if (bid >= a.blkoff[3]) r = 3;
    int i = (bid - a.blkoff[r]) * 256 + threadIdx.x;
    if (i >= a.n4[r]) return;
    f32x4 v = *(const f32x4*)(a.src[r] + (size_t)i * 4);
    unsigned short o[4] = {f2bs(v[0]), f2bs(v[1]), f2bs(v[2]), f2bs(v[3])};
    *(unsigned long long*)(a.dst[r] + (size_t)i * 4) = *(unsigned long long*)o;
}

// ---------------- embed + LUT build + counter zeroing (1 launch) -----------
__global__ __launch_bounds__(256) void k_embed_lut(const int* __restrict__ tok,
                                                   const float* __restrict__ emb,
                                                   unsigned short* __restrict__ xb,
                                                   const float* __restrict__ w1,
                                                   const float* __restrict__ b1,
                                                   const float* __restrict__ w2,
                                                   float* __restrict__ lut,
                                                   int* __restrict__ cnt) {
    constexpr int EMB_BLOCKS = Mn * En / 256;
    if (blockIdx.x < EMB_BLOCKS) {
        int i = blockIdx.x * 256 + threadIdx.x;
        if (blockIdx.x == 0 && threadIdx.x < 64) cnt[threadIdx.x] = 0;
        int m = i >> 9;
        int e = i & 511;
        xb[i] = f2bs(emb[tok[m] * En + e]);
        return;
    }
    __shared__ float sw1[En], sb1[En], sw2[En];
    for (int e = threadIdx.x; e < En; e += 256) {
        sw1[e] = w1[e]; sb1[e] = b1[e]; sw2[e] = w2[e];
    }
    __syncthreads();
    int i = (blockIdx.x - EMB_BLOCKS) * 256 + threadIdx.x;
    if (i > LUT_N) return;
    float d = (float)i * (10.0f / (float)LUT_N);
    float acc = 0.f;
#pragma unroll 4
    for (int e = 0; e < En; ++e) {
        float s = fmaf(d, sw1[e], sb1[e]);
        float t = 1.f - 2.f / (__expf(2.f * s) + 1.f);
        acc = fmaf(t, sw2[e], acc);
    }
    lut[i] = acc;
}

// ---------------- distance bias via LUT (bf16 out) ----------------
__global__ __launch_bounds__(256) void k_distbias_lut(const float* __restrict__ dist,
                                                      const int* __restrict__ tok,
                                                      const float* __restrict__ lut,
                                                      const float* __restrict__ b2,
                                                      unsigned short* __restrict__ biasmat) {
    int i = blockIdx.x * 256 + threadIdx.x;
    float d = dist[i];
    float idx = d * ((float)LUT_N / 10.0f);
    int ii = (int)idx;
    ii = ii < 0 ? 0 : (ii > LUT_N - 1 ? LUT_N - 1 : ii);
    float frac = idx - (float)ii;
    float v0 = lut[ii], v1 = lut[ii + 1];
    float acc = fmaf(v1 - v0, frac, v0) + b2[0];
    int k = i & (Nn - 1);
    int q = (i >> 8) & (Nn - 1);
    int b = i >> 16;
    bool pad = (tok[b * Nn + k] == 0) || (tok[b * Nn + q] == 0);
    biasmat[i] = f2bs(pad ? -1e30f : acc);
}

// ---------------- fused attention (unchanged from round 15) ----------------
__global__ __launch_bounds__(256, 1) void k_attn(
        const unsigned short* __restrict__ qkvb,
        const unsigned short* __restrict__ biasmat,
        unsigned short* __restrict__ attnb) {
    __shared__ short Qs[64 * 64];
    __shared__ short Ks[256 * 64];
    __shared__ short Vs[64 * 256];
    __shared__ short Ps[64 * 256];

    const int tid = threadIdx.x;
    const int lane = tid & 63;
    const int wv = tid >> 6;
    const int q0 = blockIdx.x * 64;
    const int bh = blockIdx.y;
    const int b = bh >> 3, h = bh & 7;

    const unsigned short* Qg = qkvb + ((size_t)(b * Nn + q0)) * QKV_LD + h * DHn;
    const unsigned short* Kg = qkvb + ((size_t)(b * Nn)) * QKV_LD + En + h * DHn;
    const unsigned short* VgR = qkvb + ((size_t)(b * Nn)) * QKV_LD + 2 * En + h * DHn;

    {
        const char* src = (const char*)(Kg + (size_t)tid * QKV_LD);
#pragma unroll
        for (int c = 0; c < 8; ++c)
            *(bf16x8*)((char*)Ks + swz(tid, c * 16, 128)) =
                *(const bf16x8*)(src + c * 16);
    }
    {
        const char* src = (const char*)(VgR + (size_t)tid * QKV_LD);
#pragma unroll
        for (int c = 0; c < 8; ++c) {
            bf16x8 v = *(const bf16x8*)(src + c * 16);
#pragma unroll
            for (int j = 0; j < 8; ++j) {
                int d = c * 8 + j;
                *(short*)((char*)Vs + (d * 512 + ((tid * 2) ^ ((d & 7) << 4)))) = v[j];
            }
        }
    }
    {
        int r = tid & 63;
        const char* src = (const char*)(Qg + (size_t)r * QKV_LD);
#pragma unroll
        for (int i = 0; i < 2; ++i) {
            int cb = ((tid >> 6) * 2 + i) * 16;
            bf16x8 v = *(const bf16x8*)(src + cb);
            bf16x8 o;
#pragma unroll
            for (int j = 0; j < 8; ++j) o[j] = (short)f2bs(bf2f((unsigned short)v[j]) * 0.125f);
            *(bf16x8*)((char*)Qs + swz(r, cb, 128)) = o;
        }
    }

    const int qw = wv * 16;
    const int g  = lane >> 4;
    const int c  = lane & 15;
    f32x4 acc[16];
    {
        const unsigned short* bb = biasmat + ((size_t)b * Nn + (q0 + qw + g * 4)) * Nn;
#pragma unroll
        for (int f = 0; f < 16; ++f)
#pragma unroll
            for (int r = 0; r < 4; ++r)
                acc[f][r] = bf2f(bb[(size_t)r * Nn + f * 16 + c]);
    }

    __syncthreads();

    bf16x8 qa[2];
#pragma unroll
    for (int ks = 0; ks < 2; ++ks)
        qa[ks] = *(const bf16x8*)((const char*)Qs + swz(qw + c, ks * 64 + g * 16, 128));
#pragma unroll
    for (int f = 0; f < 16; ++f) {
#pragma unroll
        for (int ks = 0; ks < 2; ++ks) {
            bf16x8 kb = *(const bf16x8*)((const char*)Ks +
                         swz(f * 16 + c, ks * 64 + g * 16, 128));
            acc[f] = __builtin_amdgcn_mfma_f32_16x16x32_bf16(qa[ks], kb, acc[f], 0, 0, 0);
        }
    }

    float rcp[4];
#pragma unroll
    for (int r = 0; r < 4; ++r) {
        float m = acc[0][r];
#pragma unroll
        for (int f = 1; f < 16; ++f) m = fmaxf(m, acc[f][r]);
#pragma unroll
        for (int o = 1; o < 16; o <<= 1) m = fmaxf(m, __shfl_xor(m, o));
        float s = 0.f;
#pragma unroll
        for (int f = 0; f < 16; ++f) {
            float e = __expf(acc[f][r] - m);
            acc[f][r] = e;
            s += e;
        }
#pragma unroll
        for (int o = 1; o < 16; o <<= 1) s += __shfl_xor(s, o);
        rcp[r] = 1.f / s;
    }

#pragma unroll
    for (int f = 0; f < 16; ++f)
#pragma unroll
        for (int r = 0; r < 4; ++r) {
            int q = qw + g * 4 + r;
            int kx = f * 16 + c;
            *(unsigned short*)((char*)Ps + (q * 512 + ((kx * 2) ^ ((q & 7) << 4)))) =
                f2bs(acc[f][r] * rcp[r]);
        }

    f32x4 acc2[4];
#pragma unroll
    for (int fd = 0; fd < 4; ++fd) acc2[fd] = {0.f, 0.f, 0.f, 0.f};
#pragma unroll
    for (int ks2 = 0; ks2 < 8; ++ks2) {
        bf16x8 pa = *(const bf16x8*)((const char*)Ps +
                      swz(qw + c, ks2 * 64 + g * 16, 512));
#pragma unroll
        for (int fd = 0; fd < 4; ++fd) {
            bf16x8 vb = *(const bf16x8*)((const char*)Vs +
                          swz(fd * 16 + c, ks2 * 64 + g * 16, 512));
            acc2[fd] = __builtin_amdgcn_mfma_f32_16x16x32_bf16(pa, vb, acc2[fd], 0, 0, 0);
        }
    }

    unsigned short* Cg = attnb + ((size_t)(b * Nn + q0 + qw)) * En + h * DHn;
#pragma unroll
    for (int fd = 0; fd < 4; ++fd)
#pragma unroll
        for (int r = 0; r < 4; ++r)
            Cg[(size_t)(g * 4 + r) * En + fd * 16 + c] = f2bs(acc2[fd][r]);
}

// ---------------- MFMA GEMM with fused split-K collector -------------------
// MODE 0: +bias[n] -> bf16 C. MODE 1: gelu(+bias[n]) -> bf16 C.
// MODE 4: raw bf16 partial (z = split); LAST block per 64-row group collects:
//         sum partials + residual + biasv -> LayerNorm -> bf16 xout.
// MODE 5: as 4, but writes fp32 dout + pad mask (final layer).
struct CollectArgs {
    const unsigned short* xin;   // residual bf16 [Mn][En]
    const float* biasv;          // bo / b2
    const float* g;
    const float* bb;
    unsigned short* xout;        // MODE 4 out
    float* dout;                 // MODE 5 out
    const int* tok;
    int* cnt;                    // per-row-group counters
    int total;                   // contributing blocks per row group
    int nsplit;
};

template <int MODE>
__global__ __launch_bounds__(256) void k_gemm(
        const unsigned short* __restrict__ A, int lda,
        const unsigned short* __restrict__ Bw, int ldb,
        const float* __restrict__ bias,
        unsigned short* __restrict__ Cp, int ldc, long long sCz,
        int K, CollectArgs ca) {
    __shared__ short As[2][64 * 64];
    __shared__ short Bs[2][64 * 64];

    const int tid  = threadIdx.x;
    const int lane = tid & 63;
    const int wv   = tid >> 6;
    const int wr   = wv >> 1, wc = wv & 1;
    const int m0 = blockIdx.x * 64, n0 = blockIdx.y * 64;
    const int z  = blockIdx.z;

    const int r_in = lane >> 3;
    const int ch   = lane & 7;
    const size_t koff2 = (size_t)z * K * 2;

    auto stage = [&](int t, int d) {
        const size_t cb = koff2 + (size_t)t * 64 * 2;
#pragma unroll
        for (int q = 0; q < 2; ++q) {
            const int rb = q * 32 + wv * 8;
            const char* ga = (const char*)A +
                (size_t)(m0 + rb + r_in) * lda * 2 + cb + ((ch ^ r_in) << 4);
            gload_lds16(ga, &As[d][rb * 64]);
        }
#pragma unroll
        for (int q = 0; q < 2; ++q) {
            const int rb = q * 32 + wv * 8;
            const char* gb = (const char*)Bw +
                (size_t)(n0 + rb + r_in) * ldb * 2 + cb + ((ch ^ r_in) << 4);
            gload_lds16(gb, &Bs[d][rb * 64]);
        }
    };

    f32x4 acc[2][2];
#pragma unroll
    for (int i = 0; i < 2; ++i)
#pragma unroll
        for (int j = 0; j < 2; ++j) acc[i][j] = {0.f, 0.f, 0.f, 0.f};

    const int fkb  = (lane >> 4) * 16;
    const int frow = lane & 15;

    stage(0, 0);
    __syncthreads();

    int cur = 0;
    const int nt = K / 64;
    for (int t = 0; t < nt; ++t) {
        if (t + 1 < nt) stage(t + 1, cur ^ 1);
#pragma unroll
        for (int ks = 0; ks < 2; ++ks) {
            bf16x8 af[2], bfr[2];
#pragma unroll
            for (int i = 0; i < 2; ++i)
                af[i] = *(const bf16x8*)((const char*)As[cur] +
                         swz(wr * 32 + i * 16 + frow, ks * 64 + fkb, 128));
#pragma unroll
            for (int j = 0; j < 2; ++j)
                bfr[j] = *(const bf16x8*)((const char*)Bs[cur] +
                          swz(wc * 32 + j * 16 + frow, ks * 64 + fkb, 128));
#pragma unroll
            for (int i = 0; i < 2; ++i)
#pragma unroll
                for (int j = 0; j < 2; ++j)
                    acc[i][j] = __builtin_amdgcn_mfma_f32_16x16x32_bf16(
                        af[i], bfr[j], acc[i][j], 0, 0, 0);
        }
        __syncthreads();
        cur ^= 1;
    }

    // ---- write tile output / partial
#pragma unroll
    for (int i = 0; i < 2; ++i) {
#pragma unroll
        for (int j = 0; j < 2; ++j) {
            const int n = n0 + wc * 32 + j * 16 + (lane & 15);
            float bv = 0.f;
            if constexpr (MODE == 0 || MODE == 1) bv = bias[n];
#pragma unroll
            for (int r = 0; r < 4; ++r) {
                const int m = m0 + wr * 32 + i * 16 + (lane >> 4) * 4 + r;
                float v = acc[i][j][r] + bv;
                if constexpr (MODE == 1)
                    v = 0.5f * v * (1.f + erff(v * 0.70710678118654752f));
                Cp[(size_t)z * sCz + (size_t)m * ldc + n] = f2bs(v);
            }
        }
    }

    if constexpr (MODE >= 4) {
        // release partials, count arrivals, last block collects
        __threadfence();
        __syncthreads();                    // As is dead; reuse for the flag
        int* flag = (int*)&As[0][0];
        if (tid == 0) *flag = atomicAdd(&ca.cnt[blockIdx.x], 1);
        __syncthreads();
        if (*flag != ca.total - 1) return;
        if (tid == 0) atomicExch(&ca.cnt[blockIdx.x], 0);   // reset for reuse
        __threadfence();                    // acquire all partials

        // collector: wave wv -> rows [m0+wv*16, +16); lane -> 8 elems of 512
        const int e0 = lane * 8;
        for (int rr = 0; rr < 16; ++rr) {
            const int m = m0 + wv * 16 + rr;
            float v[8];
            bf16x8 xv = *(const bf16x8*)(ca.xin + (size_t)m * En + e0);
#pragma unroll
            for (int j = 0; j < 8; ++j)
                v[j] = bf2f((unsigned short)xv[j]) + ca.biasv[e0 + j];
            for (int s = 0; s < ca.nsplit; ++s) {
                bf16x8 pv = *(const bf16x8*)(Cp + (size_t)s * sCz + (size_t)m * ldc + e0);
#pragma unroll
                for (int j = 0; j < 8; ++j) v[j] += bf2f((unsigned short)pv[j]);
            }
            float s1 = 0.f, s2 = 0.f;
#pragma unroll
            for (int j = 0; j < 8; ++j) { s1 += v[j]; s2 += v[j] * v[j]; }
#pragma unroll
            for (int o = 32; o; o >>= 1) {
                s1 += __shfl_xor(s1, o);
                s2 += __shfl_xor(s2, o);
            }
            const float rE = 1.f / (float)En;
            float mean = s1 * rE;
            float var = s2 * rE - mean * mean;
            float inv = rsqrtf(var + 1e-5f);
            if constexpr (MODE == 4) {
                unsigned short ov[8];
#pragma unroll
                for (int j = 0; j < 8; ++j)
                    ov[j] = f2bs((v[j] - mean) * inv * ca.g[e0 + j] + ca.bb[e0 + j]);
                *(bf16x8*)(ca.xout + (size_t)m * En + e0) = *(bf16x8*)ov;
            } else {
                float ov[8];
#pragma unroll
                for (int j = 0; j < 8; ++j)
                    ov[j] = (v[j] - mean) * inv * ca.g[e0 + j] + ca.bb[e0 + j];
                *(f32x4*)(ca.dout + (size_t)m * En + e0)     = *(f32x4*)ov;
                *(f32x4*)(ca.dout + (size_t)m * En + e0 + 4) = *(f32x4*)(ov + 4);
                if (lane == 0)
                    ca.dout[(size_t)Mn * En + m] = (ca.tok[m] == 0) ? 1.f : 0.f;
            }
        }
    }
}

// ---------------------------------------------------------------------------
extern "C" void kernel_launch(void* const* d_in, const int* in_sizes, int n_in,
                              void* d_out, int out_size, void* d_ws, size_t ws_size,
                              hipStream_t stream) {
    const int*   tok   = (const int*)  d_in[0];
    const float* dist  = (const float*)d_in[2];
    const float* emb   = (const float*)d_in[4];
    const float* dp_w1 = (const float*)d_in[5];
    const float* dp_b1 = (const float*)d_in[6];
    const float* dp_w2 = (const float*)d_in[7];
    const float* dp_b2 = (const float*)d_in[8];
    const float* Wqkv  = (const float*)d_in[9];
    const float* bqkv  = (const float*)d_in[10];
    const float* Wo    = (const float*)d_in[11];
    const float* bo    = (const float*)d_in[12];
    const float* ln1g  = (const float*)d_in[13];
    const float* ln1b  = (const float*)d_in[14];
    const float* W1    = (const float*)d_in[15];
    const float* b1    = (const float*)d_in[16];
    const float* W2    = (const float*)d_in[17];
    const float* b2    = (const float*)d_in[18];
    const float* ln2g  = (const float*)d_in[19];
    const float* ln2b  = (const float*)d_in[20];

    char* p = (char*)d_ws;
    unsigned short* biasmat = (unsigned short*)p; p += (size_t)Bn*Nn*Nn*2;   // 1 MB
    unsigned short* xb      = (unsigned short*)p; p += (size_t)Mn*En*2;      // 2 MB
    unsigned short* qkvb    = (unsigned short*)p; p += (size_t)Mn*QKV_LD*2;  // 6 MB
    unsigned short* Sffb    = (unsigned short*)p; p += (size_t)Mn*FFn*2;     // 8 MB
    unsigned short* attnb   = (unsigned short*)p; p += (size_t)Mn*En*2;      // 2 MB
    unsigned short* yp      = (unsigned short*)p; p += (size_t)4*Mn*En*2;    // 8 MB
    float*          lut     = (float*)p;          p += (size_t)(LUT_N+8)*4;
    int*            cnt     = (int*)p;            p += 64 * 4;
    unsigned short* wqkvb   = (unsigned short*)p; p += (size_t)Ln*QKV_LD*En*2;
    unsigned short* wob     = (unsigned short*)p; p += (size_t)Ln*En*En*2;
    unsigned short* w1b     = (unsigned short*)p; p += (size_t)Ln*FFn*En*2;
    unsigned short* w2b     = (unsigned short*)p; p += (size_t)Ln*En*FFn*2;

    // one-shot weight conversion (single launch, 4 ranges)
    {
        CvtArgs a;
        a.src[0] = Wqkv; a.dst[0] = wqkvb; a.n4[0] = Ln * QKV_LD * En / 4;
        a.src[1] = Wo;   a.dst[1] = wob;   a.n4[1] = Ln * En * En / 4;
        a.src[2] = W1;   a.dst[2] = w1b;   a.n4[2] = Ln * FFn * En / 4;
        a.src[3] = W2;   a.dst[3] = w2b;   a.n4[3] = Ln * En * FFn / 4;
        a.blkoff[0] = 0;
        for (int i = 0; i < 4; ++i)
            a.blkoff[i + 1] = a.blkoff[i] + (a.n4[i] + 255) / 256;
        k_cvt<<<a.blkoff[4], 256, 0, stream>>>(a);
    }

    // embed + LUT build + counter zeroing (single launch)
    k_embed_lut<<<Mn * En / 256 + (LUT_N + 256) / 256, 256, 0, stream>>>(
        tok, emb, xb, dp_w1, dp_b1, dp_w2, lut, cnt);
    k_distbias_lut<<<Bn * Nn * Nn / 256, 256, 0, stream>>>(dist, tok, lut, dp_b2,
                                                           biasmat);

    const long long yps = (long long)Mn * En;
    const CollectArgs noca{};
    for (int l = 0; l < Ln; ++l) {
        const unsigned short* Wqkv_l = wqkvb + (size_t)l * QKV_LD * En;
        const float*          bqkv_l = bqkv  + (size_t)l * QKV_LD;
        const unsigned short* Wo_l   = wob   + (size_t)l * En * En;
        const unsigned short* W1_l   = w1b   + (size_t)l * FFn * En;
        const float*          b1_l   = b1    + (size_t)l * FFn;
        const unsigned short* W2_l   = w2b   + (size_t)l * En * FFn;

        // QKV: [2048,512] x [1536,512]^T -> bf16 [2048,1536]
        k_gemm<0><<<dim3(Mn / 64, QKV_LD / 64), 256, 0, stream>>>(
            xb, En, Wqkv_l, En, bqkv_l, qkvb, QKV_LD, 0, En, noca);

        // fused attention -> attnb
        k_attn<<<dim3(Nn / 64, Bn * Hn), 256, 0, stream>>>(qkvb, biasmat, attnb);

        // O projection split-K x2 + fused residual/bias/LN1 -> xb
        {
            CollectArgs ca;
            ca.xin = xb; ca.biasv = bo + (size_t)l * En;
            ca.g = ln1g + (size_t)l * En; ca.bb = ln1b + (size_t)l * En;
            ca.xout = xb; ca.dout = nullptr; ca.tok = tok;
            ca.cnt = cnt; ca.total = (En / 64) * 2; ca.nsplit = 2;
            k_gemm<4><<<dim3(Mn / 64, En / 64, 2), 256, 0, stream>>>(
                attnb, En, Wo_l, En, nullptr, yp, En, yps, En / 2, ca);
        }

        // FF1 + GELU
        k_gemm<1><<<dim3(Mn / 64, FFn / 64), 256, 0, stream>>>(
            xb, En, W1_l, En, b1_l, Sffb, FFn, 0, En, noca);

        // FF2 split-K x4 + fused residual/bias/LN2 -> xb (or d_out on last)
        {
            CollectArgs ca;
            ca.xin = xb; ca.biasv = b2 + (size_t)l * En;
            ca.g = ln2g + (size_t)l * En; ca.bb = ln2b + (size_t)l * En;
            ca.xout = xb; ca.dout = (float*)d_out; ca.tok = tok;
            ca.cnt = cnt + 32; ca.total = (En / 64) * 4; ca.nsplit = 4;
            if (l < Ln - 1)
                k_gemm<4><<<dim3(Mn / 64, En / 64, 4), 256, 0, stream>>>(
                    Sffb, FFn, W2_l, FFn, nullptr, yp, En, yps, FFn / 4, ca);
            else
                k_gemm<5><<<dim3(Mn / 64, En / 64, 4), 256, 0, stream>>>(
                    Sffb, FFn, W2_l, FFn, nullptr, yp, En, yps, FFn / 4, ca);
        }
    }
}

// Round 17
// 283.327 us; speedup vs baseline: 4.0257x; 4.0257x over previous
//
#include <hip/hip_runtime.h>
#include <hip/hip_bf16.h>

// ---------------------------------------------------------------------------
// SimpleGeoFormerModel: 4-layer transformer encoder. FP32 out; bf16
// activations, weights, residual chain, split-K partials; MFMA fp32 acc.
// B=8 N=256 E=512 V=512 L=4 H=8 FF=2048, dh=64.
// Round 17: REVERT round-16 collector (cross-XCD __threadfence => L2 flush
// disaster). Restores round-15 structure; adds 64x128 wide tile for FF1.
// ---------------------------------------------------------------------------

namespace {
constexpr int Bn  = 8;
constexpr int Nn  = 256;
constexpr int En  = 512;
constexpr int Ln  = 4;
constexpr int Hn  = 8;
constexpr int FFn = 2048;
constexpr int DHn = 64;
constexpr int Mn  = Bn * Nn;        // 2048 rows
constexpr int QKV_LD = 3 * En;      // 1536
constexpr int LUT_N = 4096;
}

typedef float f32x4 __attribute__((ext_vector_type(4)));
typedef short bf16x8 __attribute__((ext_vector_type(8)));

// fp32 -> bf16 round-to-nearest-even (finite inputs)
__device__ __forceinline__ unsigned short f2bs(float f) {
    union { float f; unsigned u; } v; v.f = f;
    unsigned r = v.u + 0x7FFFu + ((v.u >> 16) & 1u);
    return (unsigned short)(r >> 16);
}
__device__ __forceinline__ float bf2f(unsigned short s) {
    union { unsigned u; float f; } v;
    v.u = ((unsigned)s) << 16;
    return v.f;
}

// swizzled byte address within a row-major bf16 LDS tile (16B-unit XOR)
__device__ __forceinline__ int swz(int row, int byte_in_row, int stride_b) {
    return row * stride_b + (byte_in_row ^ ((row & 7) << 4));
}

// async global->LDS, 16B per lane; LDS dest = wave-uniform base + lane*16
__device__ __forceinline__ void gload_lds16(const void* g, void* l) {
    __builtin_amdgcn_global_load_lds(
        (const __attribute__((address_space(1))) unsigned int*)g,
        (__attribute__((address_space(3))) unsigned int*)l,
        16, 0, 0);
}

// ---------------- one-shot weight conversion (4 ranges, 1 launch) ----------
struct CvtArgs {
    const float* src[4];
    unsigned short* dst[4];
    int n4[4];
    int blkoff[5];
};
__global__ __launch_bounds__(256) void k_cvt(CvtArgs a) {
    int bid = blockIdx.x;
    int r = 0;
    if (bid >= a.blkoff[1]) r = 1;
    if (bid >= a.blkoff[2]) r = 2;
    if (bid >= a.blkoff[3]) r = 3;
    int i = (bid - a.blkoff[r]) * 256 + threadIdx.x;
    if (i >= a.n4[r]) return;
    f32x4 v = *(const f32x4*)(a.src[r] + (size_t)i * 4);
    unsigned short o[4] = {f2bs(v[0]), f2bs(v[1]), f2bs(v[2]), f2bs(v[3])};
    *(unsigned long long*)(a.dst[r] + (size_t)i * 4) = *(unsigned long long*)o;
}

// ---------------- embed (blocks 0..Mn*En/256) + LUT build (rest) -----------
__global__ __launch_bounds__(256) void k_embed_lut(const int* __restrict__ tok,
                                                   const float* __restrict__ emb,
                                                   unsigned short* __restrict__ xb,
                                                   const float* __restrict__ w1,
                                                   const float* __restrict__ b1,
                                                   const float* __restrict__ w2,
                                                   float* __restrict__ lut) {
    constexpr int EMB_BLOCKS = Mn * En / 256;
    if (blockIdx.x < EMB_BLOCKS) {
        int i = blockIdx.x * 256 + threadIdx.x;
        int m = i >> 9;
        int e = i & 511;
        xb[i] = f2bs(emb[tok[m] * En + e]);
        return;
    }
    __shared__ float sw1[En], sb1[En], sw2[En];
    for (int e = threadIdx.x; e < En; e += 256) {
        sw1[e] = w1[e]; sb1[e] = b1[e]; sw2[e] = w2[e];
    }
    __syncthreads();
    int i = (blockIdx.x - EMB_BLOCKS) * 256 + threadIdx.x;
    if (i > LUT_N) return;
    float d = (float)i * (10.0f / (float)LUT_N);
    float acc = 0.f;
#pragma unroll 4
    for (int e = 0; e < En; ++e) {
        float s = fmaf(d, sw1[e], sb1[e]);
        float t = 1.f - 2.f / (__expf(2.f * s) + 1.f);
        acc = fmaf(t, sw2[e], acc);
    }
    lut[i] = acc;
}

// ---------------- distance bias via LUT (bf16 out) ----------------
__global__ __launch_bounds__(256) void k_distbias_lut(const float* __restrict__ dist,
                                                      const int* __restrict__ tok,
                                                      const float* __restrict__ lut,
                                                      const float* __restrict__ b2,
                                                      unsigned short* __restrict__ biasmat) {
    int i = blockIdx.x * 256 + threadIdx.x;
    float d = dist[i];
    float idx = d * ((float)LUT_N / 10.0f);
    int ii = (int)idx;
    ii = ii < 0 ? 0 : (ii > LUT_N - 1 ? LUT_N - 1 : ii);
    float frac = idx - (float)ii;
    float v0 = lut[ii], v1 = lut[ii + 1];
    float acc = fmaf(v1 - v0, frac, v0) + b2[0];
    int k = i & (Nn - 1);
    int q = (i >> 8) & (Nn - 1);
    int b = i >> 16;
    bool pad = (tok[b * Nn + k] == 0) || (tok[b * Nn + q] == 0);
    biasmat[i] = f2bs(pad ? -1e30f : acc);
}

// ---------------- fused attention (unchanged round 15) ---------------------
__global__ __launch_bounds__(256, 1) void k_attn(
        const unsigned short* __restrict__ qkvb,
        const unsigned short* __restrict__ biasmat,
        unsigned short* __restrict__ attnb) {
    __shared__ short Qs[64 * 64];
    __shared__ short Ks[256 * 64];
    __shared__ short Vs[64 * 256];
    __shared__ short Ps[64 * 256];

    const int tid = threadIdx.x;
    const int lane = tid & 63;
    const int wv = tid >> 6;
    const int q0 = blockIdx.x * 64;
    const int bh = blockIdx.y;
    const int b = bh >> 3, h = bh & 7;

    const unsigned short* Qg = qkvb + ((size_t)(b * Nn + q0)) * QKV_LD + h * DHn;
    const unsigned short* Kg = qkvb + ((size_t)(b * Nn)) * QKV_LD + En + h * DHn;
    const unsigned short* VgR = qkvb + ((size_t)(b * Nn)) * QKV_LD + 2 * En + h * DHn;

    {
        const char* src = (const char*)(Kg + (size_t)tid * QKV_LD);
#pragma unroll
        for (int c = 0; c < 8; ++c)
            *(bf16x8*)((char*)Ks + swz(tid, c * 16, 128)) =
                *(const bf16x8*)(src + c * 16);
    }
    {
        const char* src = (const char*)(VgR + (size_t)tid * QKV_LD);
#pragma unroll
        for (int c = 0; c < 8; ++c) {
            bf16x8 v = *(const bf16x8*)(src + c * 16);
#pragma unroll
            for (int j = 0; j < 8; ++j) {
                int d = c * 8 + j;
                *(short*)((char*)Vs + (d * 512 + ((tid * 2) ^ ((d & 7) << 4)))) = v[j];
            }
        }
    }
    {
        int r = tid & 63;
        const char* src = (const char*)(Qg + (size_t)r * QKV_LD);
#pragma unroll
        for (int i = 0; i < 2; ++i) {
            int cb = ((tid >> 6) * 2 + i) * 16;
            bf16x8 v = *(const bf16x8*)(src + cb);
            bf16x8 o;
#pragma unroll
            for (int j = 0; j < 8; ++j) o[j] = (short)f2bs(bf2f((unsigned short)v[j]) * 0.125f);
            *(bf16x8*)((char*)Qs + swz(r, cb, 128)) = o;
        }
    }

    const int qw = wv * 16;
    const int g  = lane >> 4;
    const int c  = lane & 15;
    f32x4 acc[16];
    {
        const unsigned short* bb = biasmat + ((size_t)b * Nn + (q0 + qw + g * 4)) * Nn;
#pragma unroll
        for (int f = 0; f < 16; ++f)
#pragma unroll
            for (int r = 0; r < 4; ++r)
                acc[f][r] = bf2f(bb[(size_t)r * Nn + f * 16 + c]);
    }

    __syncthreads();

    bf16x8 qa[2];
#pragma unroll
    for (int ks = 0; ks < 2; ++ks)
        qa[ks] = *(const bf16x8*)((const char*)Qs + swz(qw + c, ks * 64 + g * 16, 128));
#pragma unroll
    for (int f = 0; f < 16; ++f) {
#pragma unroll
        for (int ks = 0; ks < 2; ++ks) {
            bf16x8 kb = *(const bf16x8*)((const char*)Ks +
                         swz(f * 16 + c, ks * 64 + g * 16, 128));
            acc[f] = __builtin_amdgcn_mfma_f32_16x16x32_bf16(qa[ks], kb, acc[f], 0, 0, 0);
        }
    }

    float rcp[4];
#pragma unroll
    for (int r = 0; r < 4; ++r) {
        float m = acc[0][r];
#pragma unroll
        for (int f = 1; f < 16; ++f) m = fmaxf(m, acc[f][r]);
#pragma unroll
        for (int o = 1; o < 16; o <<= 1) m = fmaxf(m, __shfl_xor(m, o));
        float s = 0.f;
#pragma unroll
        for (int f = 0; f < 16; ++f) {
            float e = __expf(acc[f][r] - m);
            acc[f][r] = e;
            s += e;
        }
#pragma unroll
        for (int o = 1; o < 16; o <<= 1) s += __shfl_xor(s, o);
        rcp[r] = 1.f / s;
    }

#pragma unroll
    for (int f = 0; f < 16; ++f)
#pragma unroll
        for (int r = 0; r < 4; ++r) {
            int q = qw + g * 4 + r;
            int kx = f * 16 + c;
            *(unsigned short*)((char*)Ps + (q * 512 + ((kx * 2) ^ ((q & 7) << 4)))) =
                f2bs(acc[f][r] * rcp[r]);
        }

    f32x4 acc2[4];
#pragma unroll
    for (int fd = 0; fd < 4; ++fd) acc2[fd] = {0.f, 0.f, 0.f, 0.f};
#pragma unroll
    for (int ks2 = 0; ks2 < 8; ++ks2) {
        bf16x8 pa = *(const bf16x8*)((const char*)Ps +
                      swz(qw + c, ks2 * 64 + g * 16, 512));
#pragma unroll
        for (int fd = 0; fd < 4; ++fd) {
            bf16x8 vb = *(const bf16x8*)((const char*)Vs +
                          swz(fd * 16 + c, ks2 * 64 + g * 16, 512));
            acc2[fd] = __builtin_amdgcn_mfma_f32_16x16x32_bf16(pa, vb, acc2[fd], 0, 0, 0);
        }
    }

    unsigned short* Cg = attnb + ((size_t)(b * Nn + q0 + qw)) * En + h * DHn;
#pragma unroll
    for (int fd = 0; fd < 4; ++fd)
#pragma unroll
        for (int r = 0; r < 4; ++r)
            Cg[(size_t)(g * 4 + r) * En + fd * 16 + c] = f2bs(acc2[fd][r]);
}

// ---------------- MFMA GEMM 64x64 (round-15 proven) ------------------------
// MODE 0: +bias[n]; 1: gelu(+bias[n]); 3: raw bf16 partial (split-K via z).
template <int BM, int BN, int BK, int MODE>
__global__ __launch_bounds__(256) void k_gemm(
        const unsigned short* __restrict__ A, int lda,
        const unsigned short* __restrict__ Bw, int ldb,
        const float* __restrict__ bias,
        unsigned short* __restrict__ Cp, int ldc, long long sCz,
        int K) {
    static_assert(BM == 64 && BN == 64 && BK == 64, "fixed geometry");
    __shared__ short As[2][64 * 64];
    __shared__ short Bs[2][64 * 64];

    const int tid  = threadIdx.x;
    const int lane = tid & 63;
    const int wv   = tid >> 6;
    const int wr   = wv >> 1, wc = wv & 1;
    const int m0 = blockIdx.x * BM, n0 = blockIdx.y * BN;
    const int z  = blockIdx.z;

    const int r_in = lane >> 3;
    const int ch   = lane & 7;
    const size_t koff2 = (size_t)z * K * 2;

    auto stage = [&](int t, int d) {
        const size_t cb = koff2 + (size_t)t * BK * 2;
#pragma unroll
        for (int q = 0; q < 2; ++q) {
            const int rb = q * 32 + wv * 8;
            const char* ga = (const char*)A +
                (size_t)(m0 + rb + r_in) * lda * 2 + cb + ((ch ^ r_in) << 4);
            gload_lds16(ga, &As[d][rb * 64]);
        }
#pragma unroll
        for (int q = 0; q < 2; ++q) {
            const int rb = q * 32 + wv * 8;
            const char* gb = (const char*)Bw +
                (size_t)(n0 + rb + r_in) * ldb * 2 + cb + ((ch ^ r_in) << 4);
            gload_lds16(gb, &Bs[d][rb * 64]);
        }
    };

    f32x4 acc[2][2];
#pragma unroll
    for (int i = 0; i < 2; ++i)
#pragma unroll
        for (int j = 0; j < 2; ++j) acc[i][j] = {0.f, 0.f, 0.f, 0.f};

    const int fkb  = (lane >> 4) * 16;
    const int frow = lane & 15;

    stage(0, 0);
    __syncthreads();

    int cur = 0;
    const int nt = K / BK;
    for (int t = 0; t < nt; ++t) {
        if (t + 1 < nt) stage(t + 1, cur ^ 1);
#pragma unroll
        for (int ks = 0; ks < 2; ++ks) {
            bf16x8 af[2], bfr[2];
#pragma unroll
            for (int i = 0; i < 2; ++i)
                af[i] = *(const bf16x8*)((const char*)As[cur] +
                         swz(wr * 32 + i * 16 + frow, ks * 64 + fkb, 128));
#pragma unroll
            for (int j = 0; j < 2; ++j)
                bfr[j] = *(const bf16x8*)((const char*)Bs[cur] +
                          swz(wc * 32 + j * 16 + frow, ks * 64 + fkb, 128));
#pragma unroll
            for (int i = 0; i < 2; ++i)
#pragma unroll
                for (int j = 0; j < 2; ++j)
                    acc[i][j] = __builtin_amdgcn_mfma_f32_16x16x32_bf16(
                        af[i], bfr[j], acc[i][j], 0, 0, 0);
        }
        __syncthreads();
        cur ^= 1;
    }

#pragma unroll
    for (int i = 0; i < 2; ++i) {
#pragma unroll
        for (int j = 0; j < 2; ++j) {
            const int n = n0 + wc * 32 + j * 16 + (lane & 15);
            float bv = 0.f;
            if constexpr (MODE == 0 || MODE == 1) bv = bias[n];
#pragma unroll
            for (int r = 0; r < 4; ++r) {
                const int m = m0 + wr * 32 + i * 16 + (lane >> 4) * 4 + r;
                float v = acc[i][j][r] + bv;
                if constexpr (MODE == 1)
                    v = 0.5f * v * (1.f + erff(v * 0.70710678118654752f));
                Cp[(size_t)z * sCz + (size_t)m * ldc + n] = f2bs(v);
            }
        }
    }
}

// ---------------- MFMA GEMM 64x128 wide (FF1) ------------------------------
// Same staging/swizzle scheme; 4 waves each compute 32x64 (FM=2, FN=4).
// MODE 1 epilogue (gelu + bias), bf16 out.
__global__ __launch_bounds__(256) void k_gemm_wide(
        const unsigned short* __restrict__ A, int lda,
        const unsigned short* __restrict__ Bw, int ldb,
        const float* __restrict__ bias,
        unsigned short* __restrict__ Cp, int ldc,
        int K) {
    constexpr int BK = 64;
    __shared__ short As[2][64 * 64];     // 8 KB each
    __shared__ short Bs[2][128 * 64];    // 16 KB each  (total 48 KB)

    const int tid  = threadIdx.x;
    const int lane = tid & 63;
    const int wv   = tid >> 6;
    const int wr   = wv >> 1, wc = wv & 1;      // wave -> 32x64 subtile
    const int m0 = blockIdx.x * 64, n0 = blockIdx.y * 128;

    const int r_in = lane >> 3;
    const int ch   = lane & 7;

    auto stage = [&](int t, int d) {
        const size_t cb = (size_t)t * BK * 2;
#pragma unroll
        for (int q = 0; q < 2; ++q) {
            const int rb = q * 32 + wv * 8;
            const char* ga = (const char*)A +
                (size_t)(m0 + rb + r_in) * lda * 2 + cb + ((ch ^ r_in) << 4);
            gload_lds16(ga, &As[d][rb * 64]);
        }
#pragma unroll
        for (int q = 0; q < 4; ++q) {
            const int rb = q * 32 + wv * 8;
            const char* gb = (const char*)Bw +
                (size_t)(n0 + rb + r_in) * ldb * 2 + cb + ((ch ^ r_in) << 4);
            gload_lds16(gb, &Bs[d][rb * 64]);
        }
    };

    f32x4 acc[2][4];
#pragma unroll
    for (int i = 0; i < 2; ++i)
#pragma unroll
        for (int j = 0; j < 4; ++j) acc[i][j] = {0.f, 0.f, 0.f, 0.f};

    const int fkb  = (lane >> 4) * 16;
    const int frow = lane & 15;

    stage(0, 0);
    __syncthreads();

    int cur = 0;
    const int nt = K / BK;
    for (int t = 0; t < nt; ++t) {
        if (t + 1 < nt) stage(t + 1, cur ^ 1);
#pragma unroll
        for (int ks = 0; ks < 2; ++ks) {
            bf16x8 af[2], bfr[4];
#pragma unroll
            for (int i = 0; i < 2; ++i)
                af[i] = *(const bf16x8*)((const char*)As[cur] +
                         swz(wr * 32 + i * 16 + frow, ks * 64 + fkb, 128));
#pragma unroll
            for (int j = 0; j < 4; ++j)
                bfr[j] = *(const bf16x8*)((const char*)Bs[cur] +
                          swz(wc * 64 + j * 16 + frow, ks * 64 + fkb, 128));
#pragma unroll
            for (int i = 0; i < 2; ++i)
#pragma unroll
                for (int j = 0; j < 4; ++j)
                    acc[i][j] = __builtin_amdgcn_mfma_f32_16x16x32_bf16(
                        af[i], bfr[j], acc[i][j], 0, 0, 0);
        }
        __syncthreads();
        cur ^= 1;
    }

#pragma unroll
    for (int i = 0; i < 2; ++i) {
#pragma unroll
        for (int j = 0; j < 4; ++j) {
            const int n = n0 + wc * 64 + j * 16 + (lane & 15);
            const float bv = bias[n];
#pragma unroll
            for (int r = 0; r < 4; ++r) {
                const int m = m0 + wr * 32 + i * 16 + (lane >> 4) * 4 + r;
                float v = acc[i][j][r] + bv;
                v = 0.5f * v * (1.f + erff(v * 0.70710678118654752f));
                Cp[(size_t)m * ldc + n] = f2bs(v);
            }
        }
    }
}

// ---------------- residual(bf16) + split-K bf16 partials + bias + LN -------
template <int FINAL>
__global__ __launch_bounds__(256) void k_addln(
        const unsigned short* __restrict__ xin_b,
        const unsigned short* __restrict__ yp, long long ystride, int nsplit,
        const float* __restrict__ biasv,
        const float* __restrict__ g, const float* __restrict__ bb,
        unsigned short* __restrict__ xout_b, float* __restrict__ dout,
        const int* __restrict__ tok) {
    const int row = blockIdx.x;
    const int tid = threadIdx.x;
    const size_t base = (size_t)row * En;
    const int i0 = 2 * tid;

    unsigned xv = *(const unsigned*)(xin_b + base + i0);
    float2 bv = *(const float2*)(biasv + i0);
    float v0 = bf2f((unsigned short)(xv & 0xFFFFu)) + bv.x;
    float v1 = bf2f((unsigned short)(xv >> 16)) + bv.y;
    for (int s = 0; s < nsplit; ++s) {
        unsigned pv = *(const unsigned*)(yp + (size_t)s * ystride + base + i0);
        v0 += bf2f((unsigned short)(pv & 0xFFFFu));
        v1 += bf2f((unsigned short)(pv >> 16));
    }
    float s1 = v0 + v1;
    float s2 = v0 * v0 + v1 * v1;
#pragma unroll
    for (int o = 32; o; o >>= 1) {
        s1 += __shfl_xor(s1, o);
        s2 += __shfl_xor(s2, o);
    }
    __shared__ float ws1[4], ws2[4];
    int w = tid >> 6;
    if ((tid & 63) == 0) { ws1[w] = s1; ws2[w] = s2; }
    __syncthreads();
    s1 = (ws1[0] + ws1[1]) + (ws1[2] + ws1[3]);
    s2 = (ws2[0] + ws2[1]) + (ws2[2] + ws2[3]);
    const float rE = 1.f / (float)En;
    float mean = s1 * rE;
    float var = s2 * rE - mean * mean;
    float inv = rsqrtf(var + 1e-5f);
    float2 gv = *(const float2*)(g + i0);
    float2 bbv = *(const float2*)(bb + i0);
    float o0 = (v0 - mean) * inv * gv.x + bbv.x;
    float o1 = (v1 - mean) * inv * gv.y + bbv.y;
    if constexpr (FINAL) {
        *(float2*)(dout + base + i0) = make_float2(o0, o1);
        if (tid == 0)
            dout[(size_t)Mn * En + row] = (tok[row] == 0) ? 1.f : 0.f;
    } else {
        unsigned ov = (unsigned)f2bs(o0) | ((unsigned)f2bs(o1) << 16);
        *(unsigned*)(xout_b + base + i0) = ov;
    }
}

// ---------------------------------------------------------------------------
extern "C" void kernel_launch(void* const* d_in, const int* in_sizes, int n_in,
                              void* d_out, int out_size, void* d_ws, size_t ws_size,
                              hipStream_t stream) {
    const int*   tok   = (const int*)  d_in[0];
    const float* dist  = (const float*)d_in[2];
    const float* emb   = (const float*)d_in[4];
    const float* dp_w1 = (const float*)d_in[5];
    const float* dp_b1 = (const float*)d_in[6];
    const float* dp_w2 = (const float*)d_in[7];
    const float* dp_b2 = (const float*)d_in[8];
    const float* Wqkv  = (const float*)d_in[9];
    const float* bqkv  = (const float*)d_in[10];
    const float* Wo    = (const float*)d_in[11];
    const float* bo    = (const float*)d_in[12];
    const float* ln1g  = (const float*)d_in[13];
    const float* ln1b  = (const float*)d_in[14];
    const float* W1    = (const float*)d_in[15];
    const float* b1    = (const float*)d_in[16];
    const float* W2    = (const float*)d_in[17];
    const float* b2    = (const float*)d_in[18];
    const float* ln2g  = (const float*)d_in[19];
    const float* ln2b  = (const float*)d_in[20];

    char* p = (char*)d_ws;
    unsigned short* biasmat = (unsigned short*)p; p += (size_t)Bn*Nn*Nn*2;   // 1 MB
    unsigned short* xb      = (unsigned short*)p; p += (size_t)Mn*En*2;      // 2 MB
    unsigned short* qkvb    = (unsigned short*)p; p += (size_t)Mn*QKV_LD*2;  // 6 MB
    unsigned short* Sffb    = (unsigned short*)p; p += (size_t)Mn*FFn*2;     // 8 MB
    unsigned short* attnb   = (unsigned short*)p; p += (size_t)Mn*En*2;      // 2 MB
    unsigned short* yp      = (unsigned short*)p; p += (size_t)4*Mn*En*2;    // 8 MB
    float*          lut     = (float*)p;          p += (size_t)(LUT_N+8)*4;
    unsigned short* wqkvb   = (unsigned short*)p; p += (size_t)Ln*QKV_LD*En*2;
    unsigned short* wob     = (unsigned short*)p; p += (size_t)Ln*En*En*2;
    unsigned short* w1b     = (unsigned short*)p; p += (size_t)Ln*FFn*En*2;
    unsigned short* w2b     = (unsigned short*)p; p += (size_t)Ln*En*FFn*2;

    // one-shot weight conversion (single launch, 4 ranges)
    {
        CvtArgs a;
        a.src[0] = Wqkv; a.dst[0] = wqkvb; a.n4[0] = Ln * QKV_LD * En / 4;
        a.src[1] = Wo;   a.dst[1] = wob;   a.n4[1] = Ln * En * En / 4;
        a.src[2] = W1;   a.dst[2] = w1b;   a.n4[2] = Ln * FFn * En / 4;
        a.src[3] = W2;   a.dst[3] = w2b;   a.n4[3] = Ln * En * FFn / 4;
        a.blkoff[0] = 0;
        for (int i = 0; i < 4; ++i)
            a.blkoff[i + 1] = a.blkoff[i] + (a.n4[i] + 255) / 256;
        k_cvt<<<a.blkoff[4], 256, 0, stream>>>(a);
    }

    // embed + LUT build (single launch)
    k_embed_lut<<<Mn * En / 256 + (LUT_N + 256) / 256, 256, 0, stream>>>(
        tok, emb, xb, dp_w1, dp_b1, dp_w2, lut);
    k_distbias_lut<<<Bn * Nn * Nn / 256, 256, 0, stream>>>(dist, tok, lut, dp_b2,
                                                           biasmat);

    const long long yps = (long long)Mn * En;
    for (int l = 0; l < Ln; ++l) {
        const unsigned short* Wqkv_l = wqkvb + (size_t)l * QKV_LD * En;
        const float*          bqkv_l = bqkv  + (size_t)l * QKV_LD;
        const unsigned short* Wo_l   = wob   + (size_t)l * En * En;
        const unsigned short* W1_l   = w1b   + (size_t)l * FFn * En;
        const float*          b1_l   = b1    + (size_t)l * FFn;
        const unsigned short* W2_l   = w2b   + (size_t)l * En * FFn;

        // QKV: [2048,512] x [1536,512]^T -> bf16 [2048,1536]
        k_gemm<64, 64, 64, 0>
            <<<dim3(Mn / 64, QKV_LD / 64), 256, 0, stream>>>(
            xb, En, Wqkv_l, En, bqkv_l, qkvb, QKV_LD, 0, En);

        // fused attention -> attnb
        k_attn<<<dim3(Nn / 64, Bn * Hn), 256, 0, stream>>>(qkvb, biasmat, attnb);

        // O projection, split-K x2 -> bf16 partials
        k_gemm<64, 64, 64, 3>
            <<<dim3(Mn / 64, En / 64, 2), 256, 0, stream>>>(
            attnb, En, Wo_l, En, nullptr, yp, En, yps, En / 2);
        k_addln<0><<<Mn, 256, 0, stream>>>(xb, yp, yps, 2,
                                           bo + (size_t)l * En,
                                           ln1g + (size_t)l * En, ln1b + (size_t)l * En,
                                           xb, nullptr, tok);

        // FF1 + GELU (64x128 wide tile)
        k_gemm_wide<<<dim3(Mn / 64, FFn / 128), 256, 0, stream>>>(
            xb, En, W1_l, En, b1_l, Sffb, FFn, En);

        // FF2, split-K x4 -> bf16 partials
        k_gemm<64, 64, 64, 3>
            <<<dim3(Mn / 64, En / 64, 4), 256, 0, stream>>>(
            Sffb, FFn, W2_l, FFn, nullptr, yp, En, yps, FFn / 4);

        if (l < Ln - 1) {
            k_addln<0><<<Mn, 256, 0, stream>>>(xb, yp, yps, 4,
                                               b2 + (size_t)l * En,
                                               ln2g + (size_t)l * En, ln2b + (size_t)l * En,
                                               xb, nullptr, tok);
        } else {
            // final layer: LN output (fp32) + pad mask straight to d_out
            k_addln<1><<<Mn, 256, 0, stream>>>(xb, yp, yps, 4,
                                               b2 + (size_t)l * En,
                                               ln2g + (size_t)l * En, ln2b + (size_t)l * En,
                                               nullptr, (float*)d_out, tok);
        }
    }
}